// Round 6
// baseline (487.804 us; speedup 1.0000x reference)
//
#include <hip/hip_runtime.h>
#include <hip/hip_bf16.h>
#include <math.h>

#define LSEQ 2048
#define NB 4
#define DM 1024
#define ZD 128
#define HD 2048
#define ND 16
#define NEXTD 256
#define EMA_C 64
#define EMA_NCH 32

typedef __bf16 bf16x8 __attribute__((ext_vector_type(8)));
typedef __bf16 bf16x4 __attribute__((ext_vector_type(4)));
typedef float f32x4 __attribute__((ext_vector_type(4)));
typedef unsigned char uchar;

__device__ __forceinline__ float sigm(float x){ return 1.0f/(1.0f+expf(-x)); }
__device__ __forceinline__ float silu_(float x){ return x/(1.0f+expf(-x)); }
__device__ __forceinline__ float laplacef(float x){ return 0.5f*(1.0f+erff((x-0.70710678f)*2.5066282746f)); }

__device__ __forceinline__ void load_lds16(const __bf16* g, __bf16* l){
  __builtin_amdgcn_global_load_lds((const __attribute__((address_space(1))) void*)g,
                                   (__attribute__((address_space(3))) void*)l, 16, 0, 0);
}
__device__ __forceinline__ void load_lds16b(const uchar* g, uchar* l){
  __builtin_amdgcn_global_load_lds((const __attribute__((address_space(1))) void*)g,
                                   (__attribute__((address_space(3))) void*)l, 16, 0, 0);
}
// pack 4 f32 -> 4 fp8 e4m3 bytes (OCP on gfx950)
__device__ __forceinline__ unsigned int pk4_fp8(float a, float b, float c, float d){
  int v = __builtin_amdgcn_cvt_pk_fp8_f32(a, b, 0, false);
  v = __builtin_amdgcn_cvt_pk_fp8_f32(c, d, v, true);
  return (unsigned int)v;
}

// ---------------- fused: LayerNorm + weights fp32->bf16 + EMA params ----------------
__global__ __launch_bounds__(256) void f2b_ln(const float* __restrict__ x, const float* __restrict__ lnw,
                                              const float* __restrict__ lnb, __bf16* __restrict__ xnb,
                                              const float4* __restrict__ w0, const float4* __restrict__ w1,
                                              const float4* __restrict__ w2, bf16x4* __restrict__ o0,
                                              bf16x4* __restrict__ o1, bf16x4* __restrict__ o2,
                                              const float* __restrict__ de, const float* __restrict__ al,
                                              const float* __restrict__ be, const float* __restrict__ ga,
                                              float* __restrict__ qo, float* __restrict__ wo,
                                              float* __restrict__ qco){
  const int bid = blockIdx.x;
  const int tid = threadIdx.x;
  if (bid < 8192){
    // LayerNorm row
    const long row = bid;
    float4 v = ((const float4*)(x + row*DM))[tid];
    float s = v.x+v.y+v.z+v.w;
    float ss = v.x*v.x+v.y*v.y+v.z*v.z+v.w*v.w;
#pragma unroll
    for (int o=32;o>0;o>>=1){ s += __shfl_down(s,o); ss += __shfl_down(ss,o); }
    __shared__ float red[8];
    __shared__ float mv[2];
    const int wid2 = tid>>6, lane = tid&63;
    if (lane==0){ red[wid2]=s; red[4+wid2]=ss; }
    __syncthreads();
    if (tid==0){
      float ts = red[0]+red[1]+red[2]+red[3];
      float tss = red[4]+red[5]+red[6]+red[7];
      float mean = ts*(1.0f/DM);
      float var = tss*(1.0f/DM) - mean*mean;
      mv[0]=mean; mv[1]=rsqrtf(var + 1e-5f);
    }
    __syncthreads();
    const float mean=mv[0], rs=mv[1];
    float4 wv = ((const float4*)lnw)[tid];
    float4 bv = ((const float4*)lnb)[tid];
    bf16x4 ob;
    ob[0]=(__bf16)((v.x-mean)*rs*wv.x+bv.x);
    ob[1]=(__bf16)((v.y-mean)*rs*wv.y+bv.y);
    ob[2]=(__bf16)((v.z-mean)*rs*wv.z+bv.z);
    ob[3]=(__bf16)((v.w-mean)*rs*wv.w+bv.w);
    ((bf16x4*)(xnb + row*DM))[tid]=ob;
    return;
  }
  const int wb = bid - 8192;
  if (wb >= 8320){
    const int i = (wb-8320)*256 + tid;
    const float p = sigm(de[i]);
    const float q = 1.0f - p*sigm(al[i]);
    qo[i] = q;
    wo[i] = p*be[i]*ga[i]*0.25f;
    qco[i] = powf(q, (float)EMA_C);
    return;
  }
  const int i = wb*256 + tid;
  const int n0 = 524288, n1 = 1081344, n2 = 524288;
  const float4* src; bf16x4* dst; int k;
  if (i < n0){ src = w0; dst = o0; k = i; }
  else if (i < n0+n1){ src = w1; dst = o1; k = i-n0; }
  else if (i < n0+n1+n2){ src = w2; dst = o2; k = i-n0-n1; }
  else return;
  float4 v = src[k];
  bf16x4 o; o[0]=(__bf16)v.x; o[1]=(__bf16)v.y; o[2]=(__bf16)v.z; o[3]=(__bf16)v.w;
  dst[k] = o;
}

// ---------------- EMA pass A ----------------
__global__ __launch_bounds__(64) void ema_chunk_k(const __bf16* __restrict__ xn, const float* __restrict__ qp,
                                                  float* __restrict__ E){
  const int d = blockIdx.x*64 + threadIdx.x;
  const int j = blockIdx.y, b = blockIdx.z;
  float q[ND], s[ND];
#pragma unroll
  for (int n=0;n<ND;n++){ q[n]=qp[d*ND+n]; s[n]=0.0f; }
  const __bf16* xc = xn + (long)b*DM + d + (long)j*EMA_C*(NB*DM);
#pragma unroll
  for (int lt=0; lt<EMA_C; lt+=4){
    float xv[4];
#pragma unroll
    for (int u=0;u<4;u++) xv[u] = (float)xc[(long)(lt+u)*(NB*DM)];
#pragma unroll
    for (int u=0;u<4;u++)
#pragma unroll
      for (int n=0;n<ND;n++) s[n] = fmaf(q[n], s[n], xv[u]);
  }
  float4* Eo = (float4*)(E + (((long)b*EMA_NCH + j)*DM + d)*ND);
#pragma unroll
  for (int n=0;n<4;n++) Eo[n] = make_float4(s[4*n], s[4*n+1], s[4*n+2], s[4*n+3]);
}

// ---------------- EMA pass B ----------------
__global__ __launch_bounds__(256) void ema_scan_k(const float* __restrict__ E, const float* __restrict__ qc,
                                                  float* __restrict__ Sinit){
  const int t = blockIdx.x*256 + threadIdx.x;
  const int b = t >> 14;
  const int rem = t & 16383;
  const float q64 = qc[rem];
  float s = 0.0f;
  const long base = (long)b*EMA_NCH*16384 + rem;
  for (int j=0;j<EMA_NCH;j++){
    const long idx = base + (long)j*16384;
    Sinit[idx] = s;
    s = fmaf(q64, s, E[idx]);
  }
}

// ---------------- EMA pass C ----------------
__global__ __launch_bounds__(64) void ema_out_k(const __bf16* __restrict__ xn, const float* __restrict__ qp,
                                                const float* __restrict__ wp, const float* __restrict__ omega,
                                                const float* __restrict__ Sinit, __bf16* __restrict__ mx){
  const int d = blockIdx.x*64 + threadIdx.x;
  const int j = blockIdx.y, b = blockIdx.z;
  float q[ND], w[ND], s[ND];
  const float4* Si = (const float4*)(Sinit + (((long)b*EMA_NCH + j)*DM + d)*ND);
#pragma unroll
  for (int n=0;n<4;n++){ float4 v=Si[n]; s[4*n]=v.x; s[4*n+1]=v.y; s[4*n+2]=v.z; s[4*n+3]=v.w; }
#pragma unroll
  for (int n=0;n<ND;n++){ q[n]=qp[d*ND+n]; w[n]=wp[d*ND+n]; }
  const float om = omega[d];
  const int l0 = j*EMA_C;
  const __bf16* xc = xn + (long)b*DM + d;
#pragma unroll
  for (int lt=0; lt<EMA_C; lt+=4){
    float xv[4];
#pragma unroll
    for (int u=0;u<4;u++) xv[u] = (float)xc[(long)(l0+lt+u)*(NB*DM)];
#pragma unroll
    for (int u=0;u<4;u++){
      float a = 0.0f;
#pragma unroll
      for (int n=0;n<ND;n++){ s[n] = fmaf(q[n], s[n], xv[u]); a = fmaf(w[n], s[n], a); }
      mx[((long)(l0+lt+u)*NB + b)*DM + d] = (__bf16)silu_(a + xv[u]*om);
    }
  }
}

// Supertiled XCD remap (for gemm_bt grids): m from bx (permuted), n from by.
__device__ __forceinline__ void xcd_supertile(long& m0, long& n0, int tileDim){
  const int orig = blockIdx.y*gridDim.x + blockIdx.x;
  const int xcd = orig & 7, j = orig >> 3;
  const int mpx = gridDim.x >> 3;            // power of 2 in all launches
  const int sh = __builtin_ctz(mpx);
  m0 = (long)((xcd<<sh) + (j & (mpx-1))) * tileDim;
  n0 = (long)(j >> sh) * tileDim;
}

// ---------------- fused v-GEMM + base-GEMM (one dispatch, m97 structure) ----------------
// grid (64, 49): by<16 -> vT8 fp8 = e4m3(8*silu(xn@Wv^T+bv))^T [b][h][l]
//                by>=16 -> base = mx@Wmx^T+bmx -> u(sigm)/qk(+rotary)/r(silu)/hx(id)
__global__ __launch_bounds__(256, 4) void gemm_vbase(
    const __bf16* __restrict__ xnb, const __bf16* __restrict__ Wvb, const float* __restrict__ bv,
    const __bf16* __restrict__ mxp, const __bf16* __restrict__ Wmxb, const float* __restrict__ bmx,
    uchar* __restrict__ vT8, __bf16* __restrict__ u_o, __bf16* __restrict__ r_o, __bf16* __restrict__ hx_o,
    __bf16* __restrict__ qx, __bf16* __restrict__ kx, const float* __restrict__ qkg,
    const float* __restrict__ qkb, const float* __restrict__ ra, const float* __restrict__ rb)
{
  __shared__ __align__(16) char smem_raw[34816];
  __bf16* As = (__bf16*)smem_raw;
  __bf16* Bs = (__bf16*)(smem_raw + 16384);
  const int tid = threadIdx.x;
  const int lane = tid & 63;
  const int wid = tid >> 6;
  const bool isV = blockIdx.y < 16;
  const long n0 = (long)(isV ? blockIdx.y : blockIdx.y - 16) * 128;
  const long m0 = (long)(((blockIdx.x & 7) << 3) + (blockIdx.x >> 3)) * 128;  // supertile perm
  const __bf16* Ab = isV ? xnb : mxp;
  const __bf16* Bb = isV ? Wvb : Wmxb;
  const float* bias = isV ? bv : bmx;
  const int K = 1024;
  const int wm = wid & 1, wn = wid >> 1;
  const int lrow = lane >> 3;
  const int gchunk = (lane & 7) ^ lrow;

  f32x4 acc[4][4];
#pragma unroll
  for (int i=0;i<4;i++)
#pragma unroll
    for (int j=0;j<4;j++)
#pragma unroll
      for (int r=0;r<4;r++) acc[i][j][r] = 0.0f;

  for (int k0=0;k0<K;k0+=64){
    __syncthreads();
#pragma unroll
    for (int j=0;j<4;j++){
      const int g = j*4 + wid;
      const long ar = m0 + g*8 + lrow;
      load_lds16(Ab + ar*(long)K + (k0 + gchunk*8), &As[g*512]);
      const long br = n0 + g*8 + lrow;
      load_lds16(Bb + br*(long)K + (k0 + gchunk*8), &Bs[g*512]);
    }
    __syncthreads();
#pragma unroll
    for (int ks=0;ks<2;ks++){
      bf16x8 af[4], bfv[4];
      const int qd = (lane>>4) + ks*4;
#pragma unroll
      for (int i=0;i<4;i++){
        const int rowa = wm*64 + i*16 + (lane&15);
        af[i]  = *(const bf16x8*)&As[rowa*64 + ((qd ^ (rowa&7))<<3)];
        const int rowb = wn*64 + i*16 + (lane&15);
        bfv[i] = *(const bf16x8*)&Bs[rowb*64 + ((qd ^ (rowb&7))<<3)];
      }
#pragma unroll
      for (int i=0;i<4;i++)
#pragma unroll
        for (int j=0;j<4;j++)
          acc[i][j] = __builtin_amdgcn_mfma_f32_16x16x32_bf16(af[i], bfv[j], acc[i][j], 0, 0, 0);
    }
  }

  __bf16* st = (__bf16*)smem_raw;      // 128 x 136 bf16
  const int quad = lane >> 4;
  const int row = tid >> 1, half = tid & 1;
  const long row_g = m0 + row;

  if (!isV && n0 == DM){
    // z-strip: qx/kx cols [0,128) + fused rotary cols [128,256)
#pragma unroll
    for (int pass=0; pass<2; pass++){
      __syncthreads();
#pragma unroll
      for (int i=0;i<4;i++){
        const int tr0 = wm*64 + i*16 + quad*4;
#pragma unroll
        for (int j=0;j<4;j++){
          const int tc = wn*64 + j*16 + (lane&15);
          const float bb = bias[DM + tc];
          const float g = pass ? qkg[ZD+tc] : qkg[tc];
          const float be = pass ? qkb[ZD+tc] : qkb[tc];
          const float sc = pass ? 1.0f : (1.0f/LSEQ);
#pragma unroll
          for (int r=0;r<4;r++){
            const float s = silu_(acc[i][j][r] + bb);
            st[(tr0+r)*136 + tc] = (__bf16)((s*g + be)*sc);
          }
        }
      }
      __syncthreads();
      __bf16* dst = pass ? kx : qx;
      const long ll = row_g >> 2, b = row_g & 3;
      const long base = (b*LSEQ + ll)*NEXTD;
#pragma unroll
      for (int k=0;k<8;k++){
        bf16x8 vv = *(const bf16x8*)&st[row*136 + half*64 + k*8];
        *(bf16x8*)(dst + base + half*64 + k*8) = vv;
      }
    }
    // fused rotary extension for this tile's 32 l values
    {
      const long l0 = m0 >> 2;
      const int i = tid & 127;
      const int lsub = tid >> 7;
      const int jf = i & 63;
      const float fr = expf((float)jf * (-0.14391156831f));
      const float sgn = (i < 64) ? -1.0f : 1.0f;
      const float ra0 = ra[i], ra2 = (i<64) ? ra[i+64] : ra[i-64];
      const float rb0 = rb[i], rb2 = (i<64) ? rb[i+64] : rb[i-64];
      for (int t=0; t<16; t++){
        const long l = l0 + lsub*16 + t;
        const float ang = (float)l * fr;
        const float sn = sinf(ang), cs = cosf(ang);
        const __bf16 qb = (__bf16)(ra0*cs + sgn*ra2*sn);
        const __bf16 kb = (__bf16)(rb0*cs + sgn*rb2*sn);
#pragma unroll
        for (int b=0;b<4;b++){
          const long o = ((long)b*LSEQ + l)*NEXTD + 128 + i;
          qx[o] = qb;
          kx[o] = kb;
        }
      }
    }
    return;
  }

  // staging with transform
  __syncthreads();
#pragma unroll
  for (int i=0;i<4;i++){
    const int tr0 = wm*64 + i*16 + quad*4;
#pragma unroll
    for (int j=0;j<4;j++){
      const int tc = wn*64 + j*16 + (lane&15);
      const long col = n0 + tc;
      const float bb = bias[col];
#pragma unroll
      for (int r=0;r<4;r++){
        float c = acc[i][j][r] + bb;
        if (isV) c = silu_(c);
        else c = (col < DM) ? sigm(c) : ((col < DM+ZD+HD) ? silu_(c) : c);
        st[(tr0+r)*136 + tc] = (__bf16)c;
      }
    }
  }
  __syncthreads();

  if (isV){
    // direct transposed fp8 store: vT8[b][h][l] = e4m3(8 * silu(...))
    const long l0v = m0 >> 2;
    const int hl = tid & 127;
    const int b0 = tid >> 7;
#pragma unroll
    for (int bb=0; bb<2; bb++){
      const int b = b0 + 2*bb;
      unsigned int pk[8];
#pragma unroll
      for (int k=0;k<8;k++){
        float a0 = 8.0f*(float)st[((k*4+0)*4+b)*136 + hl];
        float a1 = 8.0f*(float)st[((k*4+1)*4+b)*136 + hl];
        float a2 = 8.0f*(float)st[((k*4+2)*4+b)*136 + hl];
        float a3 = 8.0f*(float)st[((k*4+3)*4+b)*136 + hl];
        pk[k] = pk4_fp8(a0,a1,a2,a3);
      }
      uchar* dst = vT8 + ((long)b*HD + n0 + hl)*LSEQ + l0v;
      *(uint4*)dst      = make_uint4(pk[0],pk[1],pk[2],pk[3]);
      *(uint4*)(dst+16) = make_uint4(pk[4],pk[5],pk[6],pk[7]);
    }
  } else {
    __bf16* dst; long ld, coff;
    if (n0 < DM)            { dst = u_o;  ld = DM; coff = n0; }
    else if (n0 < DM+ZD+HD) { dst = r_o;  ld = HD; coff = n0-DM-ZD; }
    else                    { dst = hx_o; ld = DM; coff = n0-DM-ZD-HD; }
    const long base = row_g*ld + coff + half*64;
#pragma unroll
    for (int k=0;k<8;k++){
      bf16x8 vv = *(const bf16x8*)&st[row*136 + half*64 + k*8];
      *(bf16x8*)(dst + base + k*8) = vv;
    }
  }
}

// ---------------- bf16 GEMM template (m97 structure) ----------------
// MODE 2: S8 fp8 = e4m3(16*laplace(qx@kx^T))   MODE 4: final fused f32 out
template<int MODE>
__global__ __launch_bounds__(256, 4) void gemm_bt(
    const __bf16* __restrict__ A, const __bf16* __restrict__ Bw,
    int K, long aBatch, long bBatch, const float* __restrict__ bias,
    void* __restrict__ o0, const void* __restrict__ x0, const void* __restrict__ x1,
    const void* __restrict__ x2)
{
  __shared__ __align__(16) char smem_raw[34816];
  __bf16* As = (__bf16*)smem_raw;
  __bf16* Bs = (__bf16*)(smem_raw + 16384);
  const int tid = threadIdx.x;
  const int lane = tid & 63;
  const int wid = tid >> 6;
  const int bz = blockIdx.z;
  long m0, n0;
  xcd_supertile(m0, n0, 128);
  const __bf16* Ab = A + (long)bz * aBatch;
  const __bf16* Bb = Bw + (long)bz * bBatch;
  const int wm = wid & 1, wn = wid >> 1;
  const int lrow = lane >> 3;
  const int gchunk = (lane & 7) ^ lrow;

  f32x4 acc[4][4];
#pragma unroll
  for (int i=0;i<4;i++)
#pragma unroll
    for (int j=0;j<4;j++)
#pragma unroll
      for (int r=0;r<4;r++) acc[i][j][r] = 0.0f;

  for (int k0=0;k0<K;k0+=64){
    __syncthreads();
#pragma unroll
    for (int j=0;j<4;j++){
      const int g = j*4 + wid;
      const long ar = m0 + g*8 + lrow;
      load_lds16(Ab + ar*(long)K + (k0 + gchunk*8), &As[g*512]);
      const long br = n0 + g*8 + lrow;
      load_lds16(Bb + br*(long)K + (k0 + gchunk*8), &Bs[g*512]);
    }
    __syncthreads();
#pragma unroll
    for (int ks=0;ks<2;ks++){
      bf16x8 af[4], bfv[4];
      const int qd = (lane>>4) + ks*4;
#pragma unroll
      for (int i=0;i<4;i++){
        const int rowa = wm*64 + i*16 + (lane&15);
        af[i]  = *(const bf16x8*)&As[rowa*64 + ((qd ^ (rowa&7))<<3)];
        const int rowb = wn*64 + i*16 + (lane&15);
        bfv[i] = *(const bf16x8*)&Bs[rowb*64 + ((qd ^ (rowb&7))<<3)];
      }
#pragma unroll
      for (int i=0;i<4;i++)
#pragma unroll
        for (int j=0;j<4;j++)
          acc[i][j] = __builtin_amdgcn_mfma_f32_16x16x32_bf16(af[i], bfv[j], acc[i][j], 0, 0, 0);
    }
  }

  __bf16* st = (__bf16*)smem_raw;      // 128 x 136 bf16
  float*  stf = (float*)smem_raw;      // 128 x 68 f32
  const int quad = lane >> 4;
  const int row = tid >> 1, half = tid & 1;
  const long row_g = m0 + row;

  if (MODE == 4){
#pragma unroll
    for (int p=0;p<2;p++){
      __syncthreads();
      if (wn == p){
#pragma unroll
        for (int i=0;i<4;i++){
          const int tr0 = wm*64 + i*16 + quad*4;
#pragma unroll
          for (int j=0;j<4;j++){
            const int tc = j*16 + (lane&15);
            const float bb = bias[n0 + p*64 + tc];
#pragma unroll
            for (int r=0;r<4;r++) stf[(tr0+r)*68 + tc] = acc[i][j][r] + bb;
          }
        }
      }
      __syncthreads();
#pragma unroll
      for (int k=0;k<8;k++){
        f32x4 c4 = *(const f32x4*)&stf[row*68 + half*32 + k*4];
        const long cg = n0 + p*64 + half*32 + k*4;
        const long idx = row_g*DM + cg;
        bf16x4 h4 = *(const bf16x4*)((const __bf16*)x0 + idx);
        bf16x4 u4 = *(const bf16x4*)((const __bf16*)x1 + idx);
        float4 xv = *(const float4*)((const float*)x2 + idx);
        float4 o;
        o.x = xv.x + (float)u4[0]*(silu_((float)h4[0]+c4[0]) - xv.x);
        o.y = xv.y + (float)u4[1]*(silu_((float)h4[1]+c4[1]) - xv.y);
        o.z = xv.z + (float)u4[2]*(silu_((float)h4[2]+c4[2]) - xv.z);
        o.w = xv.w + (float)u4[3]*(silu_((float)h4[3]+c4[3]) - xv.w);
        *(float4*)((float*)o0 + idx) = o;
      }
    }
    return;
  }

  // MODE 2: S8 fp8 staging (laplace*16)
  __syncthreads();
#pragma unroll
  for (int i=0;i<4;i++){
    const int tr0 = wm*64 + i*16 + quad*4;
#pragma unroll
    for (int j=0;j<4;j++){
      const int tc = wn*64 + j*16 + (lane&15);
#pragma unroll
      for (int r=0;r<4;r++)
        st[(tr0+r)*136 + tc] = (__bf16)(laplacef(acc[i][j][r])*16.0f);
    }
  }
  __syncthreads();
  {
    uchar* dst = (uchar*)o0;
    const long base = (long)bz*LSEQ*LSEQ + row_g*LSEQ + n0 + half*64;
#pragma unroll
    for (int k=0;k<4;k++){
      bf16x8 v0 = *(const bf16x8*)&st[row*136 + half*64 + k*16];
      bf16x8 v1 = *(const bf16x8*)&st[row*136 + half*64 + k*16 + 8];
      uint4 ov;
      ov.x = pk4_fp8((float)v0[0],(float)v0[1],(float)v0[2],(float)v0[3]);
      ov.y = pk4_fp8((float)v0[4],(float)v0[5],(float)v0[6],(float)v0[7]);
      ov.z = pk4_fp8((float)v1[0],(float)v1[1],(float)v1[2],(float)v1[3]);
      ov.w = pk4_fp8((float)v1[4],(float)v1[5],(float)v1[6],(float)v1[7]);
      *(uint4*)(dst + base + k*16) = ov;
    }
  }
}

// ---------------- fp8 GEMM: a3 = (S8 @ vT8^T)/128 * r ----------------
__global__ __launch_bounds__(256, 4) void gemm_fp8_att(
    const uchar* __restrict__ S8, const uchar* __restrict__ V8,
    const __bf16* __restrict__ rgate, __bf16* __restrict__ a3)
{
  __shared__ __align__(16) char smem_raw[34816];
  uchar* As = (uchar*)smem_raw;
  uchar* Bs = (uchar*)smem_raw + 8192;
  const int tid = threadIdx.x;
  const int lane = tid & 63;
  const int wid = tid >> 6;
  const int bz = blockIdx.z;
  long m0, n0;
  xcd_supertile(m0, n0, 128);
  const uchar* Ab = S8 + (long)bz * LSEQ * LSEQ;
  const uchar* Bb = V8 + (long)bz * (long)HD * LSEQ;
  const int wm = wid & 1, wn = wid >> 1;
  const int srow = lane >> 2;
  const int schunk = lane & 3;

  f32x4 acc[4][4];
#pragma unroll
  for (int i=0;i<4;i++)
#pragma unroll
    for (int j=0;j<4;j++)
#pragma unroll
      for (int r=0;r<4;r++) acc[i][j][r] = 0.0f;

  for (int k0=0;k0<LSEQ;k0+=64){
    __syncthreads();
#pragma unroll
    for (int j=0;j<2;j++){
      const int g = j*4 + wid;
      const int rr = g*16 + srow;
      const int gc = schunk ^ ((rr>>1)&3);
      load_lds16b(Ab + (m0+rr)*(long)LSEQ + k0 + gc*16, &As[g*1024]);
      load_lds16b(Bb + (n0+rr)*(long)LSEQ + k0 + gc*16, &Bs[g*1024]);
    }
    __syncthreads();
#pragma unroll
    for (int mi=0;mi<2;mi++){
      const int g = mi*4 + (lane>>4);
      long af[4], bfr[4];
#pragma unroll
      for (int i=0;i<4;i++){
        const int ra = wm*64 + i*16 + (lane&15);
        af[i]  = *(const long*)&As[ra*64 + ((g ^ (ra&6))<<3)];
        const int rb = wn*64 + i*16 + (lane&15);
        bfr[i] = *(const long*)&Bs[rb*64 + ((g ^ (rb&6))<<3)];
      }
#pragma unroll
      for (int i=0;i<4;i++)
#pragma unroll
        for (int j=0;j<4;j++)
          acc[i][j] = __builtin_amdgcn_mfma_f32_16x16x32_fp8_fp8(af[i], bfr[j], acc[i][j], 0, 0, 0);
    }
  }

  __bf16* st = (__bf16*)smem_raw;
  const int quad = lane >> 4;
  const int row = tid >> 1, half = tid & 1;
  const long row_g = m0 + row;
  __syncthreads();
#pragma unroll
  for (int i=0;i<4;i++){
    const int tr0 = wm*64 + i*16 + quad*4;
#pragma unroll
    for (int j=0;j<4;j++){
      const int tc = wn*64 + j*16 + (lane&15);
#pragma unroll
      for (int r=0;r<4;r++)
        st[(tr0+r)*136 + tc] = (__bf16)(acc[i][j][r] * (1.0f/128.0f));
    }
  }
  __syncthreads();
  const long base = (row_g*NB + bz)*HD + n0 + half*64;
#pragma unroll
  for (int k=0;k<8;k++){
    bf16x8 vv = *(const bf16x8*)&st[row*136 + half*64 + k*8];
    bf16x8 rv = *(const bf16x8*)(rgate + base + k*8);
    bf16x8 ov;
#pragma unroll
    for (int e=0;e<8;e++) ov[e] = (__bf16)((float)vv[e]*(float)rv[e]);
    *(bf16x8*)(a3 + base + k*8) = ov;
  }
}

extern "C" void kernel_launch(void* const* d_in, const int* in_sizes, int n_in,
                              void* d_out, int out_size, void* d_ws, size_t ws_size,
                              hipStream_t stream) {
  const float* x      = (const float*)d_in[0];
  const float* edelta = (const float*)d_in[1];
  const float* ealpha = (const float*)d_in[2];
  const float* ebeta  = (const float*)d_in[3];
  const float* egamma = (const float*)d_in[4];
  const float* eomega = (const float*)d_in[5];
  const float* lnw    = (const float*)d_in[6];
  const float* lnb    = (const float*)d_in[7];
  const float* Wv     = (const float*)d_in[8];
  const float* bv     = (const float*)d_in[9];
  const float* Wmx    = (const float*)d_in[10];
  const float* bmx    = (const float*)d_in[11];
  const float* Wh     = (const float*)d_in[12];
  const float* bh     = (const float*)d_in[13];
  const float* qkg    = (const float*)d_in[14];
  const float* qkb    = (const float*)d_in[15];
  const float* ralpha = (const float*)d_in[16];
  const float* rbeta  = (const float*)d_in[17];
  float* out = (float*)d_out;

  char* ws = (char*)d_ws;
  size_t off = 0;
  auto alloc = [&](size_t bytes) -> char* {
    char* p = ws + off; off = (off + bytes + 255) & ~(size_t)255; return p;
  };
  char* p_S8   = alloc(16777216);  // S fp8 [b][l][m] (laplace*16)
  char* p_xnb  = alloc(16777216);  // xn bf16 [l][b][d]
  char* p_qx   = alloc(4194304);   // qx bf16 [b][l][256]
  char* p_kx   = alloc(4194304);   // kx bf16 [b][l][256]
  char* p_mx   = alloc(16777216);  // mx bf16 [l][b][d]
  char* p_wvb  = alloc(4194304);
  char* p_wmxb = alloc(8650752);
  char* p_whb  = alloc(4194304);
  char* p_eq   = alloc(65536);
  char* p_ew   = alloc(65536);
  char* p_qc   = alloc(65536);
  char* p_v    = alloc(33554432);  // workspace for a3 bf16 [l][b][h]
  char* p_vT8  = alloc(16777216);  // vT fp8 [b][h][l] (v*8)
  char* p_u    = alloc(16777216);  // u bf16 ; EMA aliases: E(8MB)+Sinit(8MB)
  char* p_r    = alloc(33554432);  // r bf16 [l][b][h]
  char* p_hx   = alloc(16777216);  // hx bf16

  float* p_E  = (float*)p_u;
  float* p_si = (float*)(p_u + 8388608);

  // LayerNorm + weights->bf16 + EMA params (one dispatch)
  f2b_ln<<<16576, 256, 0, stream>>>(x, lnw, lnb, (__bf16*)p_xnb,
                                    (const float4*)Wv, (const float4*)Wmx, (const float4*)Wh,
                                    (bf16x4*)p_wvb, (bf16x4*)p_wmxb, (bf16x4*)p_whb,
                                    edelta, ealpha, ebeta, egamma,
                                    (float*)p_eq, (float*)p_ew, (float*)p_qc);

  ema_chunk_k<<<dim3(16,EMA_NCH,4), 64, 0, stream>>>((const __bf16*)p_xnb, (const float*)p_eq, p_E);
  ema_scan_k<<<256, 256, 0, stream>>>(p_E, (const float*)p_qc, p_si);
  ema_out_k<<<dim3(16,EMA_NCH,4), 64, 0, stream>>>((const __bf16*)p_xnb, (const float*)p_eq,
                                                   (const float*)p_ew, eomega, p_si, (__bf16*)p_mx);

  // fused: vT8 = fp8(8*silu(xn@Wv^T+bv))^T  AND  base = mx@Wmx^T+bmx -> u/(qx,kx+rot)/r/hx
  gemm_vbase<<<dim3(64,49,1), 256, 0, stream>>>((const __bf16*)p_xnb, (const __bf16*)p_wvb, bv,
      (const __bf16*)p_mx, (const __bf16*)p_wmxb, bmx,
      (uchar*)p_vT8, (__bf16*)p_u, (__bf16*)p_r, (__bf16*)p_hx,
      (__bf16*)p_qx, (__bf16*)p_kx, qkg, qkb, ralpha, rbeta);

  // S8 = fp8(16 * laplace(qx @ kx^T))
  gemm_bt<2><<<dim3(16,16,4), 256, 0, stream>>>((const __bf16*)p_qx, (const __bf16*)p_kx,
      256, (long)LSEQ*NEXTD, (long)LSEQ*NEXTD, nullptr, p_S8, nullptr, nullptr, nullptr);

  // a3 = (S8 @ vT8^T)/128 * r
  __bf16* a3 = (__bf16*)p_v;
  gemm_fp8_att<<<dim3(16,16,4), 256, 0, stream>>>((const uchar*)p_S8, (const uchar*)p_vT8,
      (const __bf16*)p_r, a3);

  // out = x + u*(silu(hx + a3 @ Wh^T + bh) - x)
  gemm_bt<4><<<dim3(64,8,1), 256, 0, stream>>>(a3, (const __bf16*)p_whb,
      2048, 0, 0, bh, out, p_hx, p_u, x);
}

// Round 7
// 482.240 us; speedup vs baseline: 1.0115x; 1.0115x over previous
//
#include <hip/hip_runtime.h>
#include <hip/hip_bf16.h>
#include <math.h>

#define LSEQ 2048
#define NB 4
#define DM 1024
#define ZD 128
#define HD 2048
#define ND 16
#define EMA_C 64
#define EMA_NCH 32

typedef __bf16 bf16x8 __attribute__((ext_vector_type(8)));
typedef __bf16 bf16x4 __attribute__((ext_vector_type(4)));
typedef float f32x4 __attribute__((ext_vector_type(4)));
typedef unsigned char uchar;

__device__ __forceinline__ float sigm(float x){ return 1.0f/(1.0f+__expf(-x)); }
__device__ __forceinline__ float silu_(float x){ return x/(1.0f+__expf(-x)); }
__device__ __forceinline__ float laplacef(float x){ return 0.5f*(1.0f+erff((x-0.70710678f)*2.5066282746f)); }

__device__ __forceinline__ void load_lds16(const __bf16* g, __bf16* l){
  __builtin_amdgcn_global_load_lds((const __attribute__((address_space(1))) void*)g,
                                   (__attribute__((address_space(3))) void*)l, 16, 0, 0);
}
__device__ __forceinline__ void load_lds16b(const uchar* g, uchar* l){
  __builtin_amdgcn_global_load_lds((const __attribute__((address_space(1))) void*)g,
                                   (__attribute__((address_space(3))) void*)l, 16, 0, 0);
}
// pack 4 f32 -> 4 fp8 e4m3 bytes (OCP on gfx950)
__device__ __forceinline__ unsigned int pk4_fp8(float a, float b, float c, float d){
  int v = __builtin_amdgcn_cvt_pk_fp8_f32(a, b, 0, false);
  v = __builtin_amdgcn_cvt_pk_fp8_f32(c, d, v, true);
  return (unsigned int)v;
}

// ---- fused: LayerNorm + weights fp32->bf16 + EMA params + Toeplitz rotary table ----
// bias[l,m] = rot(a)@rot(b)^T depends only on d=l-m:
//   g[d] = sum_j P_j cos(d f_j) + Q_j sin(d f_j),  P=a1b1+a2b2, Q=a1b2-a2b1.
__global__ __launch_bounds__(256) void f2b_ln(const float* __restrict__ x, const float* __restrict__ lnw,
                                              const float* __restrict__ lnb, __bf16* __restrict__ xnb,
                                              const float4* __restrict__ w0, const float4* __restrict__ w1,
                                              const float4* __restrict__ w2, bf16x4* __restrict__ o0,
                                              bf16x4* __restrict__ o1, bf16x4* __restrict__ o2,
                                              const float* __restrict__ de, const float* __restrict__ al,
                                              const float* __restrict__ be, const float* __restrict__ ga,
                                              float* __restrict__ qo, float* __restrict__ wo,
                                              float* __restrict__ qco,
                                              const float* __restrict__ ra, const float* __restrict__ rb,
                                              float* __restrict__ gt){
  const int bid = blockIdx.x;
  const int tid = threadIdx.x;
  if (bid < 8192){
    // LayerNorm row
    const long row = bid;
    float4 v = ((const float4*)(x + row*DM))[tid];
    float s = v.x+v.y+v.z+v.w;
    float ss = v.x*v.x+v.y*v.y+v.z*v.z+v.w*v.w;
#pragma unroll
    for (int o=32;o>0;o>>=1){ s += __shfl_down(s,o); ss += __shfl_down(ss,o); }
    __shared__ float red[8];
    __shared__ float mv[2];
    const int wid2 = tid>>6, lane = tid&63;
    if (lane==0){ red[wid2]=s; red[4+wid2]=ss; }
    __syncthreads();
    if (tid==0){
      float ts = red[0]+red[1]+red[2]+red[3];
      float tss = red[4]+red[5]+red[6]+red[7];
      float mean = ts*(1.0f/DM);
      float var = tss*(1.0f/DM) - mean*mean;
      mv[0]=mean; mv[1]=rsqrtf(var + 1e-5f);
    }
    __syncthreads();
    const float mean=mv[0], rs=mv[1];
    float4 wv = ((const float4*)lnw)[tid];
    float4 bv = ((const float4*)lnb)[tid];
    bf16x4 ob;
    ob[0]=(__bf16)((v.x-mean)*rs*wv.x+bv.x);
    ob[1]=(__bf16)((v.y-mean)*rs*wv.y+bv.y);
    ob[2]=(__bf16)((v.z-mean)*rs*wv.z+bv.z);
    ob[3]=(__bf16)((v.w-mean)*rs*wv.w+bv.w);
    ((bf16x4*)(xnb + row*DM))[tid]=ob;
    return;
  }
  const int wb = bid - 8192;
  if (wb >= 8384){
    // Toeplitz rotary-bias table: idx 0..4095, d = idx-2047
    const int idx = (wb-8384)*256 + tid;
    const float d = (float)(idx - 2047);
    float acc = 0.0f;
    for (int j=0;j<64;j++){
      const float fj = expf((float)j * (-0.14391156831f));
      const float a1 = ra[j], a2 = ra[j+64];
      const float b1 = rb[j], b2 = rb[j+64];
      const float P = a1*b1 + a2*b2;
      const float Q = a1*b2 - a2*b1;
      const float ang = d * fj;
      acc += P*cosf(ang) + Q*sinf(ang);
    }
    gt[idx] = acc;
    return;
  }
  if (wb >= 8320){
    const int i = (wb-8320)*256 + tid;
    const float p = sigm(de[i]);
    const float q = 1.0f - p*sigm(al[i]);
    qo[i] = q;
    wo[i] = p*be[i]*ga[i]*0.25f;
    qco[i] = powf(q, (float)EMA_C);
    return;
  }
  const int i = wb*256 + tid;
  const int n0 = 524288, n1 = 1081344, n2 = 524288;
  const float4* src; bf16x4* dst; int k;
  if (i < n0){ src = w0; dst = o0; k = i; }
  else if (i < n0+n1){ src = w1; dst = o1; k = i-n0; }
  else if (i < n0+n1+n2){ src = w2; dst = o2; k = i-n0-n1; }
  else return;
  float4 v = src[k];
  bf16x4 o; o[0]=(__bf16)v.x; o[1]=(__bf16)v.y; o[2]=(__bf16)v.z; o[3]=(__bf16)v.w;
  dst[k] = o;
}

// ---------------- EMA pass A ----------------
__global__ __launch_bounds__(64) void ema_chunk_k(const __bf16* __restrict__ xn, const float* __restrict__ qp,
                                                  float* __restrict__ E){
  const int d = blockIdx.x*64 + threadIdx.x;
  const int j = blockIdx.y, b = blockIdx.z;
  float q[ND], s[ND];
#pragma unroll
  for (int n=0;n<ND;n++){ q[n]=qp[d*ND+n]; s[n]=0.0f; }
  const __bf16* xc = xn + (long)b*DM + d + (long)j*EMA_C*(NB*DM);
#pragma unroll
  for (int lt=0; lt<EMA_C; lt+=4){
    float xv[4];
#pragma unroll
    for (int u=0;u<4;u++) xv[u] = (float)xc[(long)(lt+u)*(NB*DM)];
#pragma unroll
    for (int u=0;u<4;u++)
#pragma unroll
      for (int n=0;n<ND;n++) s[n] = fmaf(q[n], s[n], xv[u]);
  }
  float4* Eo = (float4*)(E + (((long)b*EMA_NCH + j)*DM + d)*ND);
#pragma unroll
  for (int n=0;n<4;n++) Eo[n] = make_float4(s[4*n], s[4*n+1], s[4*n+2], s[4*n+3]);
}

// ---------------- EMA pass B ----------------
__global__ __launch_bounds__(256) void ema_scan_k(const float* __restrict__ E, const float* __restrict__ qc,
                                                  float* __restrict__ Sinit){
  const int t = blockIdx.x*256 + threadIdx.x;
  const int b = t >> 14;
  const int rem = t & 16383;
  const float q64 = qc[rem];
  float s = 0.0f;
  const long base = (long)b*EMA_NCH*16384 + rem;
  for (int j=0;j<EMA_NCH;j++){
    const long idx = base + (long)j*16384;
    Sinit[idx] = s;
    s = fmaf(q64, s, E[idx]);
  }
}

// ---------------- EMA pass C ----------------
__global__ __launch_bounds__(64) void ema_out_k(const __bf16* __restrict__ xn, const float* __restrict__ qp,
                                                const float* __restrict__ wp, const float* __restrict__ omega,
                                                const float* __restrict__ Sinit, __bf16* __restrict__ mx){
  const int d = blockIdx.x*64 + threadIdx.x;
  const int j = blockIdx.y, b = blockIdx.z;
  float q[ND], w[ND], s[ND];
  const float4* Si = (const float4*)(Sinit + (((long)b*EMA_NCH + j)*DM + d)*ND);
#pragma unroll
  for (int n=0;n<4;n++){ float4 v=Si[n]; s[4*n]=v.x; s[4*n+1]=v.y; s[4*n+2]=v.z; s[4*n+3]=v.w; }
#pragma unroll
  for (int n=0;n<ND;n++){ q[n]=qp[d*ND+n]; w[n]=wp[d*ND+n]; }
  const float om = omega[d];
  const int l0 = j*EMA_C;
  const __bf16* xc = xn + (long)b*DM + d;
#pragma unroll
  for (int lt=0; lt<EMA_C; lt+=4){
    float xv[4];
#pragma unroll
    for (int u=0;u<4;u++) xv[u] = (float)xc[(long)(l0+lt+u)*(NB*DM)];
#pragma unroll
    for (int u=0;u<4;u++){
      float a = 0.0f;
#pragma unroll
      for (int n=0;n<ND;n++){ s[n] = fmaf(q[n], s[n], xv[u]); a = fmaf(w[n], s[n], a); }
      mx[((long)(l0+lt+u)*NB + b)*DM + d] = (__bf16)silu_(a + xv[u]*om);
    }
  }
}

// Supertiled XCD remap (for gemm_bt grids): m from bx (permuted), n from by.
__device__ __forceinline__ void xcd_supertile(long& m0, long& n0, int tileDim){
  const int orig = blockIdx.y*gridDim.x + blockIdx.x;
  const int xcd = orig & 7, j = orig >> 3;
  const int mpx = gridDim.x >> 3;            // power of 2 in all launches
  const int sh = __builtin_ctz(mpx);
  m0 = (long)((xcd<<sh) + (j & (mpx-1))) * tileDim;
  n0 = (long)(j >> sh) * tileDim;
}

// ---------------- fused v-GEMM + base-GEMM (one dispatch, m97 structure) ----------------
// grid (64, 49): by<16 -> vT8 fp8 = e4m3(8*silu(xn@Wv^T+bv))^T [b][h][l]
//                by>=16 -> base = mx@Wmx^T+bmx -> u(sigm)/qk(128-wide)/r(silu)/hx(id)
__global__ __launch_bounds__(256, 4) void gemm_vbase(
    const __bf16* __restrict__ xnb, const __bf16* __restrict__ Wvb, const float* __restrict__ bv,
    const __bf16* __restrict__ mxp, const __bf16* __restrict__ Wmxb, const float* __restrict__ bmx,
    uchar* __restrict__ vT8, __bf16* __restrict__ u_o, __bf16* __restrict__ r_o, __bf16* __restrict__ hx_o,
    __bf16* __restrict__ qx, __bf16* __restrict__ kx, const float* __restrict__ qkg,
    const float* __restrict__ qkb)
{
  __shared__ __align__(16) char smem_raw[34816];
  __bf16* As = (__bf16*)smem_raw;
  __bf16* Bs = (__bf16*)(smem_raw + 16384);
  const int tid = threadIdx.x;
  const int lane = tid & 63;
  const int wid = tid >> 6;
  const bool isV = blockIdx.y < 16;
  const long n0 = (long)(isV ? blockIdx.y : blockIdx.y - 16) * 128;
  const long m0 = (long)(((blockIdx.x & 7) << 3) + (blockIdx.x >> 3)) * 128;  // supertile perm
  const __bf16* Ab = isV ? xnb : mxp;
  const __bf16* Bb = isV ? Wvb : Wmxb;
  const float* bias = isV ? bv : bmx;
  const int K = 1024;
  const int wm = wid & 1, wn = wid >> 1;
  const int lrow = lane >> 3;
  const int gchunk = (lane & 7) ^ lrow;

  f32x4 acc[4][4];
#pragma unroll
  for (int i=0;i<4;i++)
#pragma unroll
    for (int j=0;j<4;j++)
#pragma unroll
      for (int r=0;r<4;r++) acc[i][j][r] = 0.0f;

  for (int k0=0;k0<K;k0+=64){
    __syncthreads();
#pragma unroll
    for (int j=0;j<4;j++){
      const int g = j*4 + wid;
      const long ar = m0 + g*8 + lrow;
      load_lds16(Ab + ar*(long)K + (k0 + gchunk*8), &As[g*512]);
      const long br = n0 + g*8 + lrow;
      load_lds16(Bb + br*(long)K + (k0 + gchunk*8), &Bs[g*512]);
    }
    __syncthreads();
#pragma unroll
    for (int ks=0;ks<2;ks++){
      bf16x8 af[4], bfv[4];
      const int qd = (lane>>4) + ks*4;
#pragma unroll
      for (int i=0;i<4;i++){
        const int rowa = wm*64 + i*16 + (lane&15);
        af[i]  = *(const bf16x8*)&As[rowa*64 + ((qd ^ (rowa&7))<<3)];
        const int rowb = wn*64 + i*16 + (lane&15);
        bfv[i] = *(const bf16x8*)&Bs[rowb*64 + ((qd ^ (rowb&7))<<3)];
      }
#pragma unroll
      for (int i=0;i<4;i++)
#pragma unroll
        for (int j=0;j<4;j++)
          acc[i][j] = __builtin_amdgcn_mfma_f32_16x16x32_bf16(af[i], bfv[j], acc[i][j], 0, 0, 0);
    }
  }

  __bf16* st = (__bf16*)smem_raw;      // 128 x 136 bf16
  const int quad = lane >> 4;
  const int row = tid >> 1, half = tid & 1;
  const long row_g = m0 + row;

  if (!isV && n0 == DM){
    // z-strip: qx/kx 128-wide (rotary bias handled by Toeplitz table in S-GEMM)
#pragma unroll
    for (int pass=0; pass<2; pass++){
      __syncthreads();
#pragma unroll
      for (int i=0;i<4;i++){
        const int tr0 = wm*64 + i*16 + quad*4;
#pragma unroll
        for (int j=0;j<4;j++){
          const int tc = wn*64 + j*16 + (lane&15);
          const float bb = bias[DM + tc];
          const float g = pass ? qkg[ZD+tc] : qkg[tc];
          const float be = pass ? qkb[ZD+tc] : qkb[tc];
          const float sc = pass ? 1.0f : (1.0f/LSEQ);
#pragma unroll
          for (int r=0;r<4;r++){
            const float s = silu_(acc[i][j][r] + bb);
            st[(tr0+r)*136 + tc] = (__bf16)((s*g + be)*sc);
          }
        }
      }
      __syncthreads();
      __bf16* dst = pass ? kx : qx;
      const long ll = row_g >> 2, b = row_g & 3;
      const long base = (b*LSEQ + ll)*ZD;
#pragma unroll
      for (int k=0;k<8;k++){
        bf16x8 vv = *(const bf16x8*)&st[row*136 + half*64 + k*8];
        *(bf16x8*)(dst + base + half*64 + k*8) = vv;
      }
    }
    return;
  }

  // staging with transform
  __syncthreads();
#pragma unroll
  for (int i=0;i<4;i++){
    const int tr0 = wm*64 + i*16 + quad*4;
#pragma unroll
    for (int j=0;j<4;j++){
      const int tc = wn*64 + j*16 + (lane&15);
      const long col = n0 + tc;
      const float bb = bias[col];
#pragma unroll
      for (int r=0;r<4;r++){
        float c = acc[i][j][r] + bb;
        if (isV) c = silu_(c);
        else c = (col < DM) ? sigm(c) : ((col < DM+ZD+HD) ? silu_(c) : c);
        st[(tr0+r)*136 + tc] = (__bf16)c;
      }
    }
  }
  __syncthreads();

  if (isV){
    // direct transposed fp8 store: vT8[b][h][l] = e4m3(8 * silu(...))
    const long l0v = m0 >> 2;
    const int hl = tid & 127;
    const int b0 = tid >> 7;
#pragma unroll
    for (int bb=0; bb<2; bb++){
      const int b = b0 + 2*bb;
      unsigned int pk[8];
#pragma unroll
      for (int k=0;k<8;k++){
        float a0 = 8.0f*(float)st[((k*4+0)*4+b)*136 + hl];
        float a1 = 8.0f*(float)st[((k*4+1)*4+b)*136 + hl];
        float a2 = 8.0f*(float)st[((k*4+2)*4+b)*136 + hl];
        float a3 = 8.0f*(float)st[((k*4+3)*4+b)*136 + hl];
        pk[k] = pk4_fp8(a0,a1,a2,a3);
      }
      uchar* dst = vT8 + ((long)b*HD + n0 + hl)*LSEQ + l0v;
      *(uint4*)dst      = make_uint4(pk[0],pk[1],pk[2],pk[3]);
      *(uint4*)(dst+16) = make_uint4(pk[4],pk[5],pk[6],pk[7]);
    }
  } else {
    __bf16* dst; long ld, coff;
    if (n0 < DM)            { dst = u_o;  ld = DM; coff = n0; }
    else if (n0 < DM+ZD+HD) { dst = r_o;  ld = HD; coff = n0-DM-ZD; }
    else                    { dst = hx_o; ld = DM; coff = n0-DM-ZD-HD; }
    const long base = row_g*ld + coff + half*64;
#pragma unroll
    for (int k=0;k<8;k++){
      bf16x8 vv = *(const bf16x8*)&st[row*136 + half*64 + k*8];
      *(bf16x8*)(dst + base + k*8) = vv;
    }
  }
}

// ---------------- bf16 GEMM template (m97 structure) ----------------
// MODE 2: S8 fp8 = e4m3(16*laplace(qk + g[l-m]))  (bias = Toeplitz table)
// MODE 4: final fused f32 out
template<int MODE>
__global__ __launch_bounds__(256, 4) void gemm_bt(
    const __bf16* __restrict__ A, const __bf16* __restrict__ Bw,
    int K, long aBatch, long bBatch, const float* __restrict__ bias,
    void* __restrict__ o0, const void* __restrict__ x0, const void* __restrict__ x1,
    const void* __restrict__ x2)
{
  __shared__ __align__(16) char smem_raw[34816];
  __bf16* As = (__bf16*)smem_raw;
  __bf16* Bs = (__bf16*)(smem_raw + 16384);
  const int tid = threadIdx.x;
  const int lane = tid & 63;
  const int wid = tid >> 6;
  const int bz = blockIdx.z;
  long m0, n0;
  xcd_supertile(m0, n0, 128);
  const __bf16* Ab = A + (long)bz * aBatch;
  const __bf16* Bb = Bw + (long)bz * bBatch;
  const int wm = wid & 1, wn = wid >> 1;
  const int lrow = lane >> 3;
  const int gchunk = (lane & 7) ^ lrow;

  f32x4 acc[4][4];
#pragma unroll
  for (int i=0;i<4;i++)
#pragma unroll
    for (int j=0;j<4;j++)
#pragma unroll
      for (int r=0;r<4;r++) acc[i][j][r] = 0.0f;

  for (int k0=0;k0<K;k0+=64){
    __syncthreads();
#pragma unroll
    for (int j=0;j<4;j++){
      const int g = j*4 + wid;
      const long ar = m0 + g*8 + lrow;
      load_lds16(Ab + ar*(long)K + (k0 + gchunk*8), &As[g*512]);
      const long br = n0 + g*8 + lrow;
      load_lds16(Bb + br*(long)K + (k0 + gchunk*8), &Bs[g*512]);
    }
    __syncthreads();
#pragma unroll
    for (int ks=0;ks<2;ks++){
      bf16x8 af[4], bfv[4];
      const int qd = (lane>>4) + ks*4;
#pragma unroll
      for (int i=0;i<4;i++){
        const int rowa = wm*64 + i*16 + (lane&15);
        af[i]  = *(const bf16x8*)&As[rowa*64 + ((qd ^ (rowa&7))<<3)];
        const int rowb = wn*64 + i*16 + (lane&15);
        bfv[i] = *(const bf16x8*)&Bs[rowb*64 + ((qd ^ (rowb&7))<<3)];
      }
#pragma unroll
      for (int i=0;i<4;i++)
#pragma unroll
        for (int j=0;j<4;j++)
          acc[i][j] = __builtin_amdgcn_mfma_f32_16x16x32_bf16(af[i], bfv[j], acc[i][j], 0, 0, 0);
    }
  }

  __bf16* st = (__bf16*)smem_raw;      // 128 x 136 bf16
  float*  stf = (float*)smem_raw;      // 128 x 68 f32
  const int quad = lane >> 4;
  const int row = tid >> 1, half = tid & 1;
  const long row_g = m0 + row;

  if (MODE == 4){
#pragma unroll
    for (int p=0;p<2;p++){
      __syncthreads();
      if (wn == p){
#pragma unroll
        for (int i=0;i<4;i++){
          const int tr0 = wm*64 + i*16 + quad*4;
#pragma unroll
          for (int j=0;j<4;j++){
            const int tc = j*16 + (lane&15);
            const float bb = bias[n0 + p*64 + tc];
#pragma unroll
            for (int r=0;r<4;r++) stf[(tr0+r)*68 + tc] = acc[i][j][r] + bb;
          }
        }
      }
      __syncthreads();
#pragma unroll
      for (int k=0;k<8;k++){
        f32x4 c4 = *(const f32x4*)&stf[row*68 + half*32 + k*4];
        const long cg = n0 + p*64 + half*32 + k*4;
        const long idx = row_g*DM + cg;
        bf16x4 h4 = *(const bf16x4*)((const __bf16*)x0 + idx);
        bf16x4 u4 = *(const bf16x4*)((const __bf16*)x1 + idx);
        float4 xv = *(const float4*)((const float*)x2 + idx);
        float4 o;
        o.x = xv.x + (float)u4[0]*(silu_((float)h4[0]+c4[0]) - xv.x);
        o.y = xv.y + (float)u4[1]*(silu_((float)h4[1]+c4[1]) - xv.y);
        o.z = xv.z + (float)u4[2]*(silu_((float)h4[2]+c4[2]) - xv.z);
        o.w = xv.w + (float)u4[3]*(silu_((float)h4[3]+c4[3]) - xv.w);
        *(float4*)((float*)o0 + idx) = o;
      }
    }
    return;
  }

  // MODE 2: S8 fp8 staging (laplace(qk + toeplitz)*16)
  __syncthreads();
#pragma unroll
  for (int i=0;i<4;i++){
    const int tr0 = wm*64 + i*16 + quad*4;
#pragma unroll
    for (int j=0;j<4;j++){
      const int tc = wn*64 + j*16 + (lane&15);
#pragma unroll
      for (int r=0;r<4;r++){
        const int dl = (int)(m0 + tr0 + r) - (int)(n0 + tc) + 2047;
        st[(tr0+r)*136 + tc] = (__bf16)(laplacef(acc[i][j][r] + bias[dl])*16.0f);
      }
    }
  }
  __syncthreads();
  {
    uchar* dst = (uchar*)o0;
    const long base = (long)bz*LSEQ*LSEQ + row_g*LSEQ + n0 + half*64;
#pragma unroll
    for (int k=0;k<4;k++){
      bf16x8 v0 = *(const bf16x8*)&st[row*136 + half*64 + k*16];
      bf16x8 v1 = *(const bf16x8*)&st[row*136 + half*64 + k*16 + 8];
      uint4 ov;
      ov.x = pk4_fp8((float)v0[0],(float)v0[1],(float)v0[2],(float)v0[3]);
      ov.y = pk4_fp8((float)v0[4],(float)v0[5],(float)v0[6],(float)v0[7]);
      ov.z = pk4_fp8((float)v1[0],(float)v1[1],(float)v1[2],(float)v1[3]);
      ov.w = pk4_fp8((float)v1[4],(float)v1[5],(float)v1[6],(float)v1[7]);
      *(uint4*)(dst + base + k*16) = ov;
    }
  }
}

// ---------------- fp8 GEMM: a3 = (S8 @ vT8^T)/128 * r ----------------
__global__ __launch_bounds__(256, 4) void gemm_fp8_att(
    const uchar* __restrict__ S8, const uchar* __restrict__ V8,
    const __bf16* __restrict__ rgate, __bf16* __restrict__ a3)
{
  __shared__ __align__(16) char smem_raw[34816];
  uchar* As = (uchar*)smem_raw;
  uchar* Bs = (uchar*)smem_raw + 8192;
  const int tid = threadIdx.x;
  const int lane = tid & 63;
  const int wid = tid >> 6;
  const int bz = blockIdx.z;
  long m0, n0;
  xcd_supertile(m0, n0, 128);
  const uchar* Ab = S8 + (long)bz * LSEQ * LSEQ;
  const uchar* Bb = V8 + (long)bz * (long)HD * LSEQ;
  const int wm = wid & 1, wn = wid >> 1;
  const int srow = lane >> 2;
  const int schunk = lane & 3;

  f32x4 acc[4][4];
#pragma unroll
  for (int i=0;i<4;i++)
#pragma unroll
    for (int j=0;j<4;j++)
#pragma unroll
      for (int r=0;r<4;r++) acc[i][j][r] = 0.0f;

  for (int k0=0;k0<LSEQ;k0+=64){
    __syncthreads();
#pragma unroll
    for (int j=0;j<2;j++){
      const int g = j*4 + wid;
      const int rr = g*16 + srow;
      const int gc = schunk ^ ((rr>>1)&3);
      load_lds16b(Ab + (m0+rr)*(long)LSEQ + k0 + gc*16, &As[g*1024]);
      load_lds16b(Bb + (n0+rr)*(long)LSEQ + k0 + gc*16, &Bs[g*1024]);
    }
    __syncthreads();
#pragma unroll
    for (int mi=0;mi<2;mi++){
      const int g = mi*4 + (lane>>4);
      long af[4], bfr[4];
#pragma unroll
      for (int i=0;i<4;i++){
        const int ra = wm*64 + i*16 + (lane&15);
        af[i]  = *(const long*)&As[ra*64 + ((g ^ (ra&6))<<3)];
        const int rb = wn*64 + i*16 + (lane&15);
        bfr[i] = *(const long*)&Bs[rb*64 + ((g ^ (rb&6))<<3)];
      }
#pragma unroll
      for (int i=0;i<4;i++)
#pragma unroll
        for (int j=0;j<4;j++)
          acc[i][j] = __builtin_amdgcn_mfma_f32_16x16x32_fp8_fp8(af[i], bfr[j], acc[i][j], 0, 0, 0);
    }
  }

  __bf16* st = (__bf16*)smem_raw;
  const int quad = lane >> 4;
  const int row = tid >> 1, half = tid & 1;
  const long row_g = m0 + row;
  __syncthreads();
#pragma unroll
  for (int i=0;i<4;i++){
    const int tr0 = wm*64 + i*16 + quad*4;
#pragma unroll
    for (int j=0;j<4;j++){
      const int tc = wn*64 + j*16 + (lane&15);
#pragma unroll
      for (int r=0;r<4;r++)
        st[(tr0+r)*136 + tc] = (__bf16)(acc[i][j][r] * (1.0f/128.0f));
    }
  }
  __syncthreads();
  const long base = (row_g*NB + bz)*HD + n0 + half*64;
#pragma unroll
  for (int k=0;k<8;k++){
    bf16x8 vv = *(const bf16x8*)&st[row*136 + half*64 + k*8];
    bf16x8 rv = *(const bf16x8*)(rgate + base + k*8);
    bf16x8 ov;
#pragma unroll
    for (int e=0;e<8;e++) ov[e] = (__bf16)((float)vv[e]*(float)rv[e]);
    *(bf16x8*)(a3 + base + k*8) = ov;
  }
}

extern "C" void kernel_launch(void* const* d_in, const int* in_sizes, int n_in,
                              void* d_out, int out_size, void* d_ws, size_t ws_size,
                              hipStream_t stream) {
  const float* x      = (const float*)d_in[0];
  const float* edelta = (const float*)d_in[1];
  const float* ealpha = (const float*)d_in[2];
  const float* ebeta  = (const float*)d_in[3];
  const float* egamma = (const float*)d_in[4];
  const float* eomega = (const float*)d_in[5];
  const float* lnw    = (const float*)d_in[6];
  const float* lnb    = (const float*)d_in[7];
  const float* Wv     = (const float*)d_in[8];
  const float* bv     = (const float*)d_in[9];
  const float* Wmx    = (const float*)d_in[10];
  const float* bmx    = (const float*)d_in[11];
  const float* Wh     = (const float*)d_in[12];
  const float* bh     = (const float*)d_in[13];
  const float* qkg    = (const float*)d_in[14];
  const float* qkb    = (const float*)d_in[15];
  const float* ralpha = (const float*)d_in[16];
  const float* rbeta  = (const float*)d_in[17];
  float* out = (float*)d_out;

  char* ws = (char*)d_ws;
  size_t off = 0;
  auto alloc = [&](size_t bytes) -> char* {
    char* p = ws + off; off = (off + bytes + 255) & ~(size_t)255; return p;
  };
  char* p_S8   = alloc(16777216);  // S fp8 [b][l][m] (laplace*16)
  char* p_xnb  = alloc(16777216);  // xn bf16 [l][b][d]
  char* p_qx   = alloc(4194304);   // qx bf16 [b][l][128]
  char* p_kx   = alloc(4194304);   // kx bf16 [b][l][128]
  char* p_mx   = alloc(16777216);  // mx bf16 [l][b][d]
  char* p_wvb  = alloc(4194304);
  char* p_wmxb = alloc(8650752);
  char* p_whb  = alloc(4194304);
  char* p_eq   = alloc(65536);
  char* p_ew   = alloc(65536);
  char* p_qc   = alloc(65536);
  char* p_gt   = alloc(65536);     // Toeplitz rotary table g[4096] f32
  char* p_v    = alloc(33554432);  // workspace for a3 bf16 [l][b][h]
  char* p_vT8  = alloc(16777216);  // vT fp8 [b][h][l] (v*8)
  char* p_u    = alloc(16777216);  // u bf16 ; EMA aliases: E(8MB)+Sinit(8MB)
  char* p_r    = alloc(33554432);  // r bf16 [l][b][h]
  char* p_hx   = alloc(16777216);  // hx bf16

  float* p_E  = (float*)p_u;
  float* p_si = (float*)(p_u + 8388608);

  // LayerNorm + weights->bf16 + EMA params + Toeplitz table (one dispatch)
  f2b_ln<<<16592, 256, 0, stream>>>(x, lnw, lnb, (__bf16*)p_xnb,
                                    (const float4*)Wv, (const float4*)Wmx, (const float4*)Wh,
                                    (bf16x4*)p_wvb, (bf16x4*)p_wmxb, (bf16x4*)p_whb,
                                    edelta, ealpha, ebeta, egamma,
                                    (float*)p_eq, (float*)p_ew, (float*)p_qc,
                                    ralpha, rbeta, (float*)p_gt);

  ema_chunk_k<<<dim3(16,EMA_NCH,4), 64, 0, stream>>>((const __bf16*)p_xnb, (const float*)p_eq, p_E);
  ema_scan_k<<<256, 256, 0, stream>>>(p_E, (const float*)p_qc, p_si);
  ema_out_k<<<dim3(16,EMA_NCH,4), 64, 0, stream>>>((const __bf16*)p_xnb, (const float*)p_eq,
                                                   (const float*)p_ew, eomega, p_si, (__bf16*)p_mx);

  // fused: vT8 = fp8(8*silu(xn@Wv^T+bv))^T  AND  base = mx@Wmx^T+bmx -> u/(qx,kx)/r/hx
  gemm_vbase<<<dim3(64,49,1), 256, 0, stream>>>((const __bf16*)p_xnb, (const __bf16*)p_wvb, bv,
      (const __bf16*)p_mx, (const __bf16*)p_wmxb, bmx,
      (uchar*)p_vT8, (__bf16*)p_u, (__bf16*)p_r, (__bf16*)p_hx,
      (__bf16*)p_qx, (__bf16*)p_kx, qkg, qkb);

  // S8 = fp8(16 * laplace(qx @ kx^T + g[l-m]))   [K=128, Toeplitz bias]
  gemm_bt<2><<<dim3(16,16,4), 256, 0, stream>>>((const __bf16*)p_qx, (const __bf16*)p_kx,
      ZD, (long)LSEQ*ZD, (long)LSEQ*ZD, (const float*)p_gt, p_S8, nullptr, nullptr, nullptr);

  // a3 = (S8 @ vT8^T)/128 * r
  __bf16* a3 = (__bf16*)p_v;
  gemm_fp8_att<<<dim3(16,16,4), 256, 0, stream>>>((const uchar*)p_S8, (const uchar*)p_vT8,
      (const __bf16*)p_r, a3);

  // out = x + u*(silu(hx + a3 @ Wh^T + bh) - x)
  gemm_bt<4><<<dim3(64,8,1), 256, 0, stream>>>(a3, (const __bf16*)p_whb,
      2048, 0, 0, bh, out, p_hx, p_u, x);
}